// Round 5
// baseline (490.804 us; speedup 1.0000x reference)
//
#include <hip/hip_runtime.h>
#include <hip/hip_cooperative_groups.h>

namespace cg = cooperative_groups;

#define NN 50000
#define NE 800000
#define HD 128
#define NB 196  // ceil(NN/256)

// ---------------- CSR build: one cooperative kernel ----------------
// phases: zero deg -> count -> block scan -> partial scan -> finalize(+dinv,cursor) -> fill

__global__ void k_csr_build(const int* __restrict__ ei, int* __restrict__ deg,
                            int* __restrict__ offs, int* __restrict__ cursor,
                            int* __restrict__ part, float* __restrict__ dinv,
                            int* __restrict__ csr) {
    cg::grid_group g = cg::this_grid();
    int t = threadIdx.x, b = blockIdx.x;
    int gt = b * 256 + t;
    const int GT = 256 * 256;  // grid-wide threads

    // a: zero
    for (int i = gt; i < NN; i += GT) deg[i] = 0;
    g.sync();

    // b: degree count
    for (int e = gt; e < NE; e += GT) atomicAdd(&deg[ei[e]], 1);
    g.sync();

    // c: block-local exclusive scan (block b owns nodes [b*256, b*256+256))
    __shared__ int s[256];
    int i = b * 256 + t;
    int v = (b < NB && i < NN) ? deg[i] : 0;
    s[t] = v;
    __syncthreads();
#pragma unroll
    for (int o = 1; o < 256; o <<= 1) {
        int x = (t >= o) ? s[t - o] : 0;
        __syncthreads();
        s[t] += x;
        __syncthreads();
    }
    if (b < NB && i < NN) offs[i] = s[t] - v;
    if (b < NB && t == 255) part[b] = s[255];
    g.sync();

    // d: scan the 196 block partials on block 0
    if (b == 0) {
        int v2 = (t < NB) ? part[t] : 0;
        s[t] = v2;
        __syncthreads();
#pragma unroll
        for (int o = 1; o < 256; o <<= 1) {
            int x = (t >= o) ? s[t - o] : 0;
            __syncthreads();
            s[t] += x;
            __syncthreads();
        }
        if (t < NB) part[t] = s[t] - v2;
    }
    g.sync();

    // e: finalize offsets, cursor copy, dinv
    if (b < NB && i < NN) {
        int o = offs[i] + part[b];
        offs[i] = o;
        cursor[i] = o;
        dinv[i] = rsqrtf((float)(deg[i] + 1));  // +1 self-loop
    }
    g.sync();

    // f: CSR fill (group source ids by destination)
    for (int e = gt; e < NE; e += GT) {
        int r = ei[e];
        int slot = atomicAdd(&cursor[r], 1);
        csr[slot] = ei[NE + e];
    }
}

// ---------------- aggregation: one wave per node, 8-deep gather pipeline ----------------
// dst[r] = dinv[r]^2 * src[r] + sum_e dinv[r]*dinv[c_e] * src[c_e]

__global__ __launch_bounds__(256) void k_agg_csr(const float* __restrict__ src,
                                                 const int* __restrict__ csr,
                                                 const int* __restrict__ offs,
                                                 const int* __restrict__ deg,
                                                 const float* __restrict__ dinv,
                                                 float* __restrict__ dst) {
    int node = blockIdx.x * 4 + (threadIdx.x >> 6);  // 4 waves/block, grid exact
    int lane = threadIdx.x & 63;
    int o = offs[node];
    int dg = deg[node];
    float d = dinv[node];

    float2 v = ((const float2*)(src + (size_t)node * HD))[lane];
    float s = d * d;
    float2 acc = make_float2(s * v.x, s * v.y);

    for (int base = 0; base < dg; base += 64) {
        int n = min(64, dg - base);
        int myc = (lane < n) ? csr[o + base + lane] : node;
        float myw = (lane < n) ? d * dinv[myc] : 0.0f;
        int j = 0;
        // 8 independent gathers in flight per wave (MLP), then the FMA block
        for (; j + 8 <= n; j += 8) {
            int c0 = __shfl(myc, j + 0), c1 = __shfl(myc, j + 1);
            int c2 = __shfl(myc, j + 2), c3 = __shfl(myc, j + 3);
            int c4 = __shfl(myc, j + 4), c5 = __shfl(myc, j + 5);
            int c6 = __shfl(myc, j + 6), c7 = __shfl(myc, j + 7);
            float w0 = __shfl(myw, j + 0), w1 = __shfl(myw, j + 1);
            float w2 = __shfl(myw, j + 2), w3 = __shfl(myw, j + 3);
            float w4 = __shfl(myw, j + 4), w5 = __shfl(myw, j + 5);
            float w6 = __shfl(myw, j + 6), w7 = __shfl(myw, j + 7);
            float2 v0 = ((const float2*)(src + (size_t)c0 * HD))[lane];
            float2 v1 = ((const float2*)(src + (size_t)c1 * HD))[lane];
            float2 v2 = ((const float2*)(src + (size_t)c2 * HD))[lane];
            float2 v3 = ((const float2*)(src + (size_t)c3 * HD))[lane];
            float2 v4 = ((const float2*)(src + (size_t)c4 * HD))[lane];
            float2 v5 = ((const float2*)(src + (size_t)c5 * HD))[lane];
            float2 v6 = ((const float2*)(src + (size_t)c6 * HD))[lane];
            float2 v7 = ((const float2*)(src + (size_t)c7 * HD))[lane];
            acc.x = fmaf(w0, v0.x, acc.x); acc.y = fmaf(w0, v0.y, acc.y);
            acc.x = fmaf(w1, v1.x, acc.x); acc.y = fmaf(w1, v1.y, acc.y);
            acc.x = fmaf(w2, v2.x, acc.x); acc.y = fmaf(w2, v2.y, acc.y);
            acc.x = fmaf(w3, v3.x, acc.x); acc.y = fmaf(w3, v3.y, acc.y);
            acc.x = fmaf(w4, v4.x, acc.x); acc.y = fmaf(w4, v4.y, acc.y);
            acc.x = fmaf(w5, v5.x, acc.x); acc.y = fmaf(w5, v5.y, acc.y);
            acc.x = fmaf(w6, v6.x, acc.x); acc.y = fmaf(w6, v6.y, acc.y);
            acc.x = fmaf(w7, v7.x, acc.x); acc.y = fmaf(w7, v7.y, acc.y);
        }
        for (; j < n; ++j) {
            int c = __shfl(myc, j);
            float w = __shfl(myw, j);
            float2 vv = ((const float2*)(src + (size_t)c * HD))[lane];
            acc.x = fmaf(w, vv.x, acc.x);
            acc.y = fmaf(w, vv.y, acc.y);
        }
    }
    ((float2*)(dst + (size_t)node * HD))[lane] = acc;
}

// ---------------- fp32 GEMM: C[nrows,128] = act(A[nrows,128] @ W[128,128] + b) -------

template <bool RELU>
__global__ __launch_bounds__(256, 2) void k_gemm(const float* __restrict__ A,
                                                 const float* __restrict__ W,
                                                 const float* __restrict__ bias,
                                                 float* __restrict__ C, int nrows) {
    __shared__ float Ws[128][128];
    __shared__ float As[128][32];
    int t = threadIdx.x;

    const float4* W4 = (const float4*)W;
#pragma unroll
    for (int u = 0; u < 16; ++u) {
        int i4 = u * 256 + t;
        ((float4*)Ws)[i4] = W4[i4];
    }

    int row0 = blockIdx.x * 128;
    int tx = t & 7;
    int ty = t >> 3;

    float acc[4][16];
#pragma unroll
    for (int m = 0; m < 4; ++m)
#pragma unroll
        for (int j = 0; j < 16; ++j) acc[m][j] = 0.0f;

    for (int kb = 0; kb < 4; ++kb) {
        __syncthreads();
#pragma unroll
        for (int u = 0; u < 4; ++u) {
            int i4 = u * 256 + t;
            int r = i4 >> 3;
            int uc = i4 & 7;
            float4 v = make_float4(0.f, 0.f, 0.f, 0.f);
            int gr = row0 + r;
            if (gr < nrows) v = *(const float4*)(A + (size_t)gr * HD + kb * 32 + uc * 4);
            int us = uc ^ ((r >> 2) & 7);
            *(float4*)&As[r][us * 4] = v;
        }
        __syncthreads();
#pragma unroll
        for (int kk = 0; kk < 32; ++kk) {
            int hi = kk >> 2, lo = kk & 3;
            float a[4];
#pragma unroll
            for (int m = 0; m < 4; ++m) {
                int r = ty * 4 + m;
                a[m] = As[r][(((hi ^ ((r >> 2) & 7)) << 2) | lo)];
            }
#pragma unroll
            for (int i = 0; i < 4; ++i) {
                float4 w = *(const float4*)&Ws[kb * 32 + kk][tx * 4 + i * 32];
#pragma unroll
                for (int m = 0; m < 4; ++m) {
                    acc[m][i * 4 + 0] = fmaf(a[m], w.x, acc[m][i * 4 + 0]);
                    acc[m][i * 4 + 1] = fmaf(a[m], w.y, acc[m][i * 4 + 1]);
                    acc[m][i * 4 + 2] = fmaf(a[m], w.z, acc[m][i * 4 + 2]);
                    acc[m][i * 4 + 3] = fmaf(a[m], w.w, acc[m][i * 4 + 3]);
                }
            }
        }
    }

#pragma unroll
    for (int m = 0; m < 4; ++m) {
        int gr = row0 + ty * 4 + m;
        if (gr >= nrows) continue;
#pragma unroll
        for (int i = 0; i < 4; ++i) {
            int cb = tx * 4 + i * 32;
            float4 b4 = *(const float4*)(bias + cb);
            float4 o;
            o.x = acc[m][i * 4 + 0] + b4.x;
            o.y = acc[m][i * 4 + 1] + b4.y;
            o.z = acc[m][i * 4 + 2] + b4.z;
            o.w = acc[m][i * 4 + 3] + b4.w;
            if (RELU) {
                o.x = fmaxf(o.x, 0.f);
                o.y = fmaxf(o.y, 0.f);
                o.z = fmaxf(o.z, 0.f);
                o.w = fmaxf(o.w, 0.f);
            }
            *(float4*)(C + (size_t)gr * HD + cb) = o;
        }
    }
}

// ---------------- launch ----------------

extern "C" void kernel_launch(void* const* d_in, const int* in_sizes, int n_in,
                              void* d_out, int out_size, void* d_ws, size_t ws_size,
                              hipStream_t stream) {
    const int*   ei = (const int*)d_in[1];
    const float* x  = (const float*)d_in[0];
    const float* W1 = (const float*)d_in[2];
    const float* b1 = (const float*)d_in[3];
    const float* W2 = (const float*)d_in[4];
    const float* b2 = (const float*)d_in[5];
    float* out = (float*)d_out;

    char* ws = (char*)d_ws;
    size_t off = 0;
    auto alloc = [&](size_t bytes) {
        void* p = ws + off;
        off = (off + bytes + 255) & ~(size_t)255;
        return p;
    };
    int*   deg    = (int*)alloc(NN * 4);
    int*   offs   = (int*)alloc(NN * 4);
    int*   cursor = (int*)alloc(NN * 4);
    int*   part   = (int*)alloc(256 * 4);
    float* dinv   = (float*)alloc(NN * 4);
    int*   csr    = (int*)alloc((size_t)NE * 4);
    float* t1     = (float*)alloc((size_t)NN * HD * 4);

    // CSR build: single cooperative kernel
    {
        void* args[] = {(void*)&ei, (void*)&deg, (void*)&offs, (void*)&cursor,
                        (void*)&part, (void*)&dinv, (void*)&csr};
        hipLaunchCooperativeKernel((void*)k_csr_build, dim3(256), dim3(256), args, 0, stream);
    }

    // conv1: t1 = agg(x); out(h) = relu(t1@W1 + b1)
    k_agg_csr<<<NN / 4, 256, 0, stream>>>(x, csr, offs, deg, dinv, t1);
    k_gemm<true><<<(NN + 127) / 128, 256, 0, stream>>>(t1, W1, b1, out, NN);

    // conv2: t1 = agg(h); out = t1@W2 + b2
    k_agg_csr<<<NN / 4, 256, 0, stream>>>(out, csr, offs, deg, dinv, t1);
    k_gemm<false><<<(NN + 127) / 128, 256, 0, stream>>>(t1, W2, b2, out, NN);
}

// Round 6
// 348.225 us; speedup vs baseline: 1.4094x; 1.4094x over previous
//
#include <hip/hip_runtime.h>

#define NN 50000
#define NE 800000
#define HD 128
#define NB 196  // ceil(NN/256)

using short8 = __attribute__((ext_vector_type(8))) short;
using f32x4  = __attribute__((ext_vector_type(4))) float;

__device__ inline unsigned short rne_bf16(float v) {
    union { float f; unsigned u; } c; c.f = v;
    return (unsigned short)((c.u + 0x7fff + ((c.u >> 16) & 1)) >> 16);
}
__device__ inline float bf16_to_f32(unsigned short h) {
    union { unsigned u; float f; } c; c.u = ((unsigned)h) << 16;
    return c.f;
}

// ---------------- CSR build (six small kernels; R4-proven) ----------------

__global__ void k_zero(int* __restrict__ p, int n) {
    int i = blockIdx.x * 256 + threadIdx.x;
    if (i < n) p[i] = 0;
}

__global__ void k_deg_count(const int* __restrict__ row, int* __restrict__ deg) {
    int e = blockIdx.x * 256 + threadIdx.x;
    if (e < NE) atomicAdd(&deg[row[e]], 1);
}

__global__ void k_scan1(const int* __restrict__ deg, int* __restrict__ offs,
                        int* __restrict__ part) {
    __shared__ int s[256];
    int t = threadIdx.x;
    int i = blockIdx.x * 256 + t;
    int v = (i < NN) ? deg[i] : 0;
    s[t] = v;
    __syncthreads();
#pragma unroll
    for (int off = 1; off < 256; off <<= 1) {
        int x = (t >= off) ? s[t - off] : 0;
        __syncthreads();
        s[t] += x;
        __syncthreads();
    }
    if (i < NN) offs[i] = s[t] - v;
    if (t == 255) part[blockIdx.x] = s[255];
}

__global__ void k_scan2(int* __restrict__ part) {
    __shared__ int s[256];
    int t = threadIdx.x;
    int v = (t < NB) ? part[t] : 0;
    s[t] = v;
    __syncthreads();
#pragma unroll
    for (int off = 1; off < 256; off <<= 1) {
        int x = (t >= off) ? s[t - off] : 0;
        __syncthreads();
        s[t] += x;
        __syncthreads();
    }
    if (t < NB) part[t] = s[t] - v;
}

__global__ void k_scan3(int* __restrict__ offs, const int* __restrict__ part,
                        const int* __restrict__ deg, int* __restrict__ cursor,
                        float* __restrict__ dinv) {
    int i = blockIdx.x * 256 + threadIdx.x;
    if (i >= NN) return;
    int o = offs[i] + part[blockIdx.x];
    offs[i] = o;
    cursor[i] = o;
    dinv[i] = rsqrtf((float)(deg[i] + 1));  // +1 self-loop
}

__global__ void k_fill(const int* __restrict__ ei, int* __restrict__ cursor,
                       int* __restrict__ csr) {
    int e = blockIdx.x * 256 + threadIdx.x;
    if (e >= NE) return;
    int r = ei[e];
    int slot = atomicAdd(&cursor[r], 1);
    csr[slot] = ei[NE + e];
}

// ---------------- weight prep: fragment-layout bf16 hi/lo split ----------------
// layout: frag[((nt*4 + ks)*64 + lane)*8 + j] = W[ks*32 + (lane>>4)*8 + j][nt*16 + (lane&15)]
// 16 blocks: b<8 -> W1, else W2. tid in [0,2048) per weight = (nt,ks,lane).

__global__ void k_prepw(const float* __restrict__ W1, const float* __restrict__ W2,
                        unsigned short* __restrict__ hi1, unsigned short* __restrict__ lo1,
                        unsigned short* __restrict__ hi2, unsigned short* __restrict__ lo2) {
    int b = blockIdx.x;
    const float* W = (b < 8) ? W1 : W2;
    unsigned short* hi = (b < 8) ? hi1 : hi2;
    unsigned short* lo = (b < 8) ? lo1 : lo2;
    int tid = (b & 7) * 256 + threadIdx.x;  // 0..2047
    int lane = tid & 63;
    int ks = (tid >> 6) & 3;
    int nt = tid >> 8;
    int n = nt * 16 + (lane & 15);
    int k0 = ks * 32 + (lane >> 4) * 8;
#pragma unroll
    for (int j = 0; j < 8; ++j) {
        float v = W[(k0 + j) * HD + n];
        unsigned short h = rne_bf16(v);
        float rem = v - bf16_to_f32(h);
        hi[(size_t)tid * 8 + j] = h;
        lo[(size_t)tid * 8 + j] = rne_bf16(rem);
    }
}

// ---------------- aggregation: one wave per node (fp32, L2-fill-bound) ----------------

__global__ __launch_bounds__(256) void k_agg_csr(const float* __restrict__ src,
                                                 const int* __restrict__ csr,
                                                 const int* __restrict__ offs,
                                                 const int* __restrict__ deg,
                                                 const float* __restrict__ dinv,
                                                 float* __restrict__ dst) {
    int node = blockIdx.x * 4 + (threadIdx.x >> 6);
    int lane = threadIdx.x & 63;
    int o = offs[node];
    int dg = deg[node];
    float d = dinv[node];

    float2 v = ((const float2*)(src + (size_t)node * HD))[lane];
    float s = d * d;
    float2 acc = make_float2(s * v.x, s * v.y);

    for (int base = 0; base < dg; base += 64) {
        int n = min(64, dg - base);
        int myc = (lane < n) ? csr[o + base + lane] : node;
        float myw = (lane < n) ? d * dinv[myc] : 0.0f;
        int j = 0;
        for (; j + 8 <= n; j += 8) {
            int c0 = __shfl(myc, j + 0), c1 = __shfl(myc, j + 1);
            int c2 = __shfl(myc, j + 2), c3 = __shfl(myc, j + 3);
            int c4 = __shfl(myc, j + 4), c5 = __shfl(myc, j + 5);
            int c6 = __shfl(myc, j + 6), c7 = __shfl(myc, j + 7);
            float w0 = __shfl(myw, j + 0), w1 = __shfl(myw, j + 1);
            float w2 = __shfl(myw, j + 2), w3 = __shfl(myw, j + 3);
            float w4 = __shfl(myw, j + 4), w5 = __shfl(myw, j + 5);
            float w6 = __shfl(myw, j + 6), w7 = __shfl(myw, j + 7);
            float2 v0 = ((const float2*)(src + (size_t)c0 * HD))[lane];
            float2 v1 = ((const float2*)(src + (size_t)c1 * HD))[lane];
            float2 v2 = ((const float2*)(src + (size_t)c2 * HD))[lane];
            float2 v3 = ((const float2*)(src + (size_t)c3 * HD))[lane];
            float2 v4 = ((const float2*)(src + (size_t)c4 * HD))[lane];
            float2 v5 = ((const float2*)(src + (size_t)c5 * HD))[lane];
            float2 v6 = ((const float2*)(src + (size_t)c6 * HD))[lane];
            float2 v7 = ((const float2*)(src + (size_t)c7 * HD))[lane];
            acc.x = fmaf(w0, v0.x, acc.x); acc.y = fmaf(w0, v0.y, acc.y);
            acc.x = fmaf(w1, v1.x, acc.x); acc.y = fmaf(w1, v1.y, acc.y);
            acc.x = fmaf(w2, v2.x, acc.x); acc.y = fmaf(w2, v2.y, acc.y);
            acc.x = fmaf(w3, v3.x, acc.x); acc.y = fmaf(w3, v3.y, acc.y);
            acc.x = fmaf(w4, v4.x, acc.x); acc.y = fmaf(w4, v4.y, acc.y);
            acc.x = fmaf(w5, v5.x, acc.x); acc.y = fmaf(w5, v5.y, acc.y);
            acc.x = fmaf(w6, v6.x, acc.x); acc.y = fmaf(w6, v6.y, acc.y);
            acc.x = fmaf(w7, v7.x, acc.x); acc.y = fmaf(w7, v7.y, acc.y);
        }
        for (; j < n; ++j) {
            int c = __shfl(myc, j);
            float w = __shfl(myw, j);
            float2 vv = ((const float2*)(src + (size_t)c * HD))[lane];
            acc.x = fmaf(w, vv.x, acc.x);
            acc.y = fmaf(w, vv.y, acc.y);
        }
    }
    ((float2*)(dst + (size_t)node * HD))[lane] = acc;
}

// ---------------- MFMA GEMM (split-bf16, fp32-accurate) ----------------
// C[nrows,128] = act(A @ W + b); wave computes 16 rows x 128 cols.
// A fp32 loaded direct, split to hi/lo bf16; W pre-fragmented (global, L2-hot).

template <bool RELU>
__global__ __launch_bounds__(256) void k_gemm_mfma(const float* __restrict__ A,
                                                   const unsigned short* __restrict__ Whi,
                                                   const unsigned short* __restrict__ Wlo,
                                                   const float* __restrict__ bias,
                                                   float* __restrict__ C, int nrows) {
    int l = threadIdx.x & 63;
    int w = threadIdx.x >> 6;
    int row0 = blockIdx.x * 64 + w * 16;
    int arow = row0 + (l & 15);
    int kj = (l >> 4) * 8;
    bool avalid = (arow < nrows);
    const float* ap = A + (size_t)(avalid ? arow : 0) * HD + kj;

    f32x4 acc[8];
#pragma unroll
    for (int nt = 0; nt < 8; ++nt) acc[nt] = (f32x4){0.f, 0.f, 0.f, 0.f};

#pragma unroll
    for (int ks = 0; ks < 4; ++ks) {
        float4 a0 = make_float4(0.f, 0.f, 0.f, 0.f), a1 = a0;
        if (avalid) {
            a0 = *(const float4*)(ap + ks * 32);
            a1 = *(const float4*)(ap + ks * 32 + 4);
        }
        float av[8] = {a0.x, a0.y, a0.z, a0.w, a1.x, a1.y, a1.z, a1.w};
        short8 ahi, alo;
#pragma unroll
        for (int j = 0; j < 8; ++j) {
            unsigned short h = rne_bf16(av[j]);
            ahi[j] = (short)h;
            alo[j] = (short)rne_bf16(av[j] - bf16_to_f32(h));
        }
#pragma unroll
        for (int nt = 0; nt < 8; ++nt) {
            size_t fo = ((size_t)(nt * 4 + ks) * 64 + l) * 8;
            short8 bhi = *(const short8*)(Whi + fo);
            short8 blo = *(const short8*)(Wlo + fo);
            acc[nt] = __builtin_amdgcn_mfma_f32_16x16x32_bf16(ahi, bhi, acc[nt], 0, 0, 0);
            acc[nt] = __builtin_amdgcn_mfma_f32_16x16x32_bf16(alo, bhi, acc[nt], 0, 0, 0);
            acc[nt] = __builtin_amdgcn_mfma_f32_16x16x32_bf16(ahi, blo, acc[nt], 0, 0, 0);
        }
    }

#pragma unroll
    for (int nt = 0; nt < 8; ++nt) {
        int col = nt * 16 + (l & 15);
        float bv = bias[col];
#pragma unroll
        for (int r = 0; r < 4; ++r) {
            int gr = row0 + (l >> 4) * 4 + r;
            if (gr >= nrows) continue;
            float v = acc[nt][r] + bv;
            if (RELU) v = fmaxf(v, 0.f);
            C[(size_t)gr * HD + col] = v;
        }
    }
}

// ---------------- launch ----------------

extern "C" void kernel_launch(void* const* d_in, const int* in_sizes, int n_in,
                              void* d_out, int out_size, void* d_ws, size_t ws_size,
                              hipStream_t stream) {
    const float* x  = (const float*)d_in[0];
    const int*   ei = (const int*)d_in[1];
    const float* W1 = (const float*)d_in[2];
    const float* b1 = (const float*)d_in[3];
    const float* W2 = (const float*)d_in[4];
    const float* b2 = (const float*)d_in[5];
    float* out = (float*)d_out;

    char* ws = (char*)d_ws;
    size_t off = 0;
    auto alloc = [&](size_t bytes) {
        void* p = ws + off;
        off = (off + bytes + 255) & ~(size_t)255;
        return p;
    };
    int*   deg    = (int*)alloc(NN * 4);
    int*   offs   = (int*)alloc(NN * 4);
    int*   cursor = (int*)alloc(NN * 4);
    int*   part   = (int*)alloc(256 * 4);
    float* dinv   = (float*)alloc(NN * 4);
    int*   csr    = (int*)alloc((size_t)NE * 4);
    float* t1     = (float*)alloc((size_t)NN * HD * 4);
    float* h      = (float*)alloc((size_t)NN * HD * 4);
    unsigned short* Whi1 = (unsigned short*)alloc(16384 * 2);
    unsigned short* Wlo1 = (unsigned short*)alloc(16384 * 2);
    unsigned short* Whi2 = (unsigned short*)alloc(16384 * 2);
    unsigned short* Wlo2 = (unsigned short*)alloc(16384 * 2);

    // CSR build
    k_zero<<<NB, 256, 0, stream>>>(deg, NN);
    k_deg_count<<<(NE + 255) / 256, 256, 0, stream>>>(ei, deg);
    k_scan1<<<NB, 256, 0, stream>>>(deg, offs, part);
    k_scan2<<<1, 256, 0, stream>>>(part);
    k_scan3<<<NB, 256, 0, stream>>>(offs, part, deg, cursor, dinv);
    k_fill<<<(NE + 255) / 256, 256, 0, stream>>>(ei, cursor, csr);

    // weight prep (independent of CSR; tiny)
    k_prepw<<<16, 256, 0, stream>>>(W1, W2, Whi1, Wlo1, Whi2, Wlo2);

    // conv1: t1 = agg(x); h = relu(t1@W1 + b1)
    k_agg_csr<<<NN / 4, 256, 0, stream>>>(x, csr, offs, deg, dinv, t1);
    k_gemm_mfma<true><<<(NN + 63) / 64, 256, 0, stream>>>(t1, Whi1, Wlo1, b1, h, NN);

    // conv2: t1 = agg(h); out = t1@W2 + b2
    k_agg_csr<<<NN / 4, 256, 0, stream>>>(h, csr, offs, deg, dinv, t1);
    k_gemm_mfma<false><<<(NN + 63) / 64, 256, 0, stream>>>(t1, Whi2, Wlo2, b2, out, NN);
}

// Round 7
// 319.319 us; speedup vs baseline: 1.5370x; 1.0905x over previous
//
#include <hip/hip_runtime.h>

#define NN 50000
#define NE 800000
#define HD 128
#define NB 196    // ceil(NN/256)
#define NBK 98    // ceil(NN/512) dst-buckets for CSR fill
#define FB 196    // fill pass-1 blocks (196*4096 >= NE)

using short8 = __attribute__((ext_vector_type(8))) short;
using f32x4  = __attribute__((ext_vector_type(4))) float;

__device__ inline unsigned short rne_bf16(float v) {
    union { float f; unsigned u; } c; c.f = v;
    return (unsigned short)((c.u + 0x7fff + ((c.u >> 16) & 1)) >> 16);
}
__device__ inline float bf16_to_f32(unsigned short h) {
    union { unsigned u; float f; } c; c.u = ((unsigned)h) << 16;
    return c.f;
}

// ---------------- degree + scan ----------------

__global__ void k_zero(int* __restrict__ p, int n) {
    int i = blockIdx.x * 256 + threadIdx.x;
    if (i < n) p[i] = 0;
}

__global__ void k_deg_count(const int* __restrict__ row, int* __restrict__ deg) {
    int e = blockIdx.x * 256 + threadIdx.x;
    if (e < NE) atomicAdd(&deg[row[e]], 1);
}

__global__ void k_scan1(const int* __restrict__ deg, int* __restrict__ offs,
                        int* __restrict__ part) {
    __shared__ int s[256];
    int t = threadIdx.x;
    int i = blockIdx.x * 256 + t;
    int v = (i < NN) ? deg[i] : 0;
    s[t] = v;
    __syncthreads();
#pragma unroll
    for (int off = 1; off < 256; off <<= 1) {
        int x = (t >= off) ? s[t - off] : 0;
        __syncthreads();
        s[t] += x;
        __syncthreads();
    }
    if (i < NN) offs[i] = s[t] - v;
    if (t == 255) part[blockIdx.x] = s[255];
}

__global__ void k_scan2(int* __restrict__ part) {
    __shared__ int s[256];
    int t = threadIdx.x;
    int v = (t < NB) ? part[t] : 0;
    s[t] = v;
    __syncthreads();
#pragma unroll
    for (int off = 1; off < 256; off <<= 1) {
        int x = (t >= off) ? s[t - off] : 0;
        __syncthreads();
        s[t] += x;
        __syncthreads();
    }
    if (t < NB) part[t] = s[t] - v;
}

__global__ void k_scan3(int* __restrict__ offs, const int* __restrict__ part,
                        const int* __restrict__ deg, float* __restrict__ dinv) {
    int i = blockIdx.x * 256 + threadIdx.x;
    if (i >= NN) return;
    offs[i] += part[blockIdx.x];
    dinv[i] = rsqrtf((float)(deg[i] + 1));  // +1 self-loop
}

// ---------------- bucketed CSR fill ----------------
// bucket b = dst >> 9 (512 nodes); pairs region of bucket b = csr region = [offs[b*512], ...)

__global__ void k_binit(const int* __restrict__ offs, int* __restrict__ bcur) {
    int i = threadIdx.x;
    if (i < NBK) bcur[i] = offs[i * 512];
}

// pass 1: bin edges into bucket-ordered pairs (dst,src), chunk-contiguous writes
__global__ __launch_bounds__(256) void k_fill1(const int* __restrict__ ei,
                                               int* __restrict__ bcur,
                                               int2* __restrict__ pairs) {
    __shared__ int dr[4096], sc[4096];
    __shared__ int hist[NBK], base[NBK];
    int t = threadIdx.x, b = blockIdx.x;
    for (int i = t; i < NBK; i += 256) hist[i] = 0;
    __syncthreads();
    int e0 = b * 4096;
#pragma unroll
    for (int u = 0; u < 16; ++u) {
        int idx = u * 256 + t, e = e0 + idx;
        int r = -1, c = 0;
        if (e < NE) {
            r = ei[e];
            c = ei[NE + e];
            atomicAdd(&hist[r >> 9], 1);
        }
        dr[idx] = r;
        sc[idx] = c;
    }
    __syncthreads();
    for (int i = t; i < NBK; i += 256) {
        base[i] = atomicAdd(&bcur[i], hist[i]);  // reserve chunk
        hist[i] = 0;                             // reuse as chunk position
    }
    __syncthreads();
#pragma unroll
    for (int u = 0; u < 16; ++u) {
        int idx = u * 256 + t;
        int r = dr[idx];
        if (r >= 0) {
            int bk = r >> 9;
            int pos = atomicAdd(&hist[bk], 1);
            pairs[base[bk] + pos] = make_int2(r, sc[idx]);
        }
    }
}

// pass 2: one block per bucket, LDS cursors, scatter into 65KB csr window
__global__ __launch_bounds__(256) void k_fill2(const int2* __restrict__ pairs,
                                               const int* __restrict__ offs,
                                               int* __restrict__ csr) {
    __shared__ int lcur[512];
    int b = blockIdx.x, t = threadIdx.x;
    int n0 = b * 512;
    int nodes = min(512, NN - n0);
    for (int i = t; i < nodes; i += 256) lcur[i] = offs[n0 + i];
    __syncthreads();
    int start = offs[n0];
    int end = (n0 + 512 >= NN) ? NE : offs[n0 + 512];
    for (int p = start + t; p < end; p += 256) {
        int2 pr = pairs[p];
        int slot = atomicAdd(&lcur[pr.x - n0], 1);
        csr[slot] = pr.y;
    }
}

// ---------------- weight prep: fragment-layout bf16 hi/lo split ----------------

__global__ void k_prepw(const float* __restrict__ W1, const float* __restrict__ W2,
                        unsigned short* __restrict__ hi1, unsigned short* __restrict__ lo1,
                        unsigned short* __restrict__ hi2, unsigned short* __restrict__ lo2) {
    int b = blockIdx.x;
    const float* W = (b < 8) ? W1 : W2;
    unsigned short* hi = (b < 8) ? hi1 : hi2;
    unsigned short* lo = (b < 8) ? lo1 : lo2;
    int tid = (b & 7) * 256 + threadIdx.x;  // 0..2047
    int lane = tid & 63;
    int ks = (tid >> 6) & 3;
    int nt = tid >> 8;
    int n = nt * 16 + (lane & 15);
    int k0 = ks * 32 + (lane >> 4) * 8;
#pragma unroll
    for (int j = 0; j < 8; ++j) {
        float v = W[(k0 + j) * HD + n];
        unsigned short h = rne_bf16(v);
        float rem = v - bf16_to_f32(h);
        hi[(size_t)tid * 8 + j] = h;
        lo[(size_t)tid * 8 + j] = rne_bf16(rem);
    }
}

// ---------------- aggregation: one wave/node, float4 gathers, 2 rows/instr ----------
// lanes 0-31 accumulate even-indexed edges, 32-63 odd; combine at end.

__global__ __launch_bounds__(256) void k_agg_csr(const float* __restrict__ src,
                                                 const int* __restrict__ csr,
                                                 const int* __restrict__ offs,
                                                 const int* __restrict__ deg,
                                                 const float* __restrict__ dinv,
                                                 float* __restrict__ dst) {
    int node = blockIdx.x * 4 + (threadIdx.x >> 6);
    int lane = threadIdx.x & 63;
    int half = lane >> 5;
    int q = lane & 31;  // float4 column index
    int o = offs[node];
    int dg = deg[node];
    float d = dinv[node];

    float4 acc = make_float4(0.f, 0.f, 0.f, 0.f);
    if (half == 0) {
        float s = d * d;
        float4 v = ((const float4*)(src + (size_t)node * HD))[q];
        acc = make_float4(s * v.x, s * v.y, s * v.z, s * v.w);
    }

    for (int base = 0; base < dg; base += 64) {
        int n = min(64, dg - base);
        int myc = (lane < n) ? csr[o + base + lane] : node;
        float myw = (lane < n) ? d * dinv[myc] : 0.0f;
        for (int j = 0; j < n; j += 16) {
            int c[8];
            float w[8];
#pragma unroll
            for (int p = 0; p < 8; ++p) {
                c[p] = __shfl(myc, j + 2 * p + half);
                w[p] = __shfl(myw, j + 2 * p + half);
            }
            float4 v[8];
#pragma unroll
            for (int p = 0; p < 8; ++p)
                v[p] = *(const float4*)(src + (size_t)c[p] * HD + q * 4);
#pragma unroll
            for (int p = 0; p < 8; ++p) {
                acc.x = fmaf(w[p], v[p].x, acc.x);
                acc.y = fmaf(w[p], v[p].y, acc.y);
                acc.z = fmaf(w[p], v[p].z, acc.z);
                acc.w = fmaf(w[p], v[p].w, acc.w);
            }
        }
    }

    // combine halves: lane q (<32) += lane q+32
    float ox = acc.x + __shfl(acc.x, q + 32);
    float oy = acc.y + __shfl(acc.y, q + 32);
    float oz = acc.z + __shfl(acc.z, q + 32);
    float ow = acc.w + __shfl(acc.w, q + 32);
    if (half == 0)
        ((float4*)(dst + (size_t)node * HD))[q] = make_float4(ox, oy, oz, ow);
}

// ---------------- MFMA GEMM (split-bf16, fp32-accurate) ----------------

template <bool RELU>
__global__ __launch_bounds__(256) void k_gemm_mfma(const float* __restrict__ A,
                                                   const unsigned short* __restrict__ Whi,
                                                   const unsigned short* __restrict__ Wlo,
                                                   const float* __restrict__ bias,
                                                   float* __restrict__ C, int nrows) {
    int l = threadIdx.x & 63;
    int w = threadIdx.x >> 6;
    int row0 = blockIdx.x * 64 + w * 16;
    int arow = row0 + (l & 15);
    int kj = (l >> 4) * 8;
    bool avalid = (arow < nrows);
    const float* ap = A + (size_t)(avalid ? arow : 0) * HD + kj;

    f32x4 acc[8];
#pragma unroll
    for (int nt = 0; nt < 8; ++nt) acc[nt] = (f32x4){0.f, 0.f, 0.f, 0.f};

#pragma unroll
    for (int ks = 0; ks < 4; ++ks) {
        float4 a0 = make_float4(0.f, 0.f, 0.f, 0.f), a1 = a0;
        if (avalid) {
            a0 = *(const float4*)(ap + ks * 32);
            a1 = *(const float4*)(ap + ks * 32 + 4);
        }
        float av[8] = {a0.x, a0.y, a0.z, a0.w, a1.x, a1.y, a1.z, a1.w};
        short8 ahi, alo;
#pragma unroll
        for (int j = 0; j < 8; ++j) {
            unsigned short h = rne_bf16(av[j]);
            ahi[j] = (short)h;
            alo[j] = (short)rne_bf16(av[j] - bf16_to_f32(h));
        }
#pragma unroll
        for (int nt = 0; nt < 8; ++nt) {
            size_t fo = ((size_t)(nt * 4 + ks) * 64 + l) * 8;
            short8 bhi = *(const short8*)(Whi + fo);
            short8 blo = *(const short8*)(Wlo + fo);
            acc[nt] = __builtin_amdgcn_mfma_f32_16x16x32_bf16(ahi, bhi, acc[nt], 0, 0, 0);
            acc[nt] = __builtin_amdgcn_mfma_f32_16x16x32_bf16(alo, bhi, acc[nt], 0, 0, 0);
            acc[nt] = __builtin_amdgcn_mfma_f32_16x16x32_bf16(ahi, blo, acc[nt], 0, 0, 0);
        }
    }

#pragma unroll
    for (int nt = 0; nt < 8; ++nt) {
        int col = nt * 16 + (l & 15);
        float bv = bias[col];
#pragma unroll
        for (int r = 0; r < 4; ++r) {
            int gr = row0 + (l >> 4) * 4 + r;
            if (gr >= nrows) continue;
            float v = acc[nt][r] + bv;
            if (RELU) v = fmaxf(v, 0.f);
            C[(size_t)gr * HD + col] = v;
        }
    }
}

// ---------------- launch ----------------

extern "C" void kernel_launch(void* const* d_in, const int* in_sizes, int n_in,
                              void* d_out, int out_size, void* d_ws, size_t ws_size,
                              hipStream_t stream) {
    const float* x  = (const float*)d_in[0];
    const int*   ei = (const int*)d_in[1];
    const float* W1 = (const float*)d_in[2];
    const float* b1 = (const float*)d_in[3];
    const float* W2 = (const float*)d_in[4];
    const float* b2 = (const float*)d_in[5];
    float* out = (float*)d_out;

    char* ws = (char*)d_ws;
    size_t off = 0;
    auto alloc = [&](size_t bytes) {
        void* p = ws + off;
        off = (off + bytes + 255) & ~(size_t)255;
        return p;
    };
    int*   deg   = (int*)alloc(NN * 4);
    int*   offs  = (int*)alloc(NN * 4);
    int*   part  = (int*)alloc(256 * 4);
    int*   bcur  = (int*)alloc(NBK * 4);
    float* dinv  = (float*)alloc(NN * 4);
    int*   csr   = (int*)alloc((size_t)NE * 4);
    int2*  pairs = (int2*)alloc((size_t)NE * 8);
    float* t1    = (float*)alloc((size_t)NN * HD * 4);
    float* h     = (float*)alloc((size_t)NN * HD * 4);
    unsigned short* Whi1 = (unsigned short*)alloc(16384 * 2);
    unsigned short* Wlo1 = (unsigned short*)alloc(16384 * 2);
    unsigned short* Whi2 = (unsigned short*)alloc(16384 * 2);
    unsigned short* Wlo2 = (unsigned short*)alloc(16384 * 2);

    // CSR build
    k_zero<<<NB, 256, 0, stream>>>(deg, NN);
    k_deg_count<<<(NE + 255) / 256, 256, 0, stream>>>(ei, deg);
    k_scan1<<<NB, 256, 0, stream>>>(deg, offs, part);
    k_scan2<<<1, 256, 0, stream>>>(part);
    k_scan3<<<NB, 256, 0, stream>>>(offs, part, deg, dinv);
    k_binit<<<1, 128, 0, stream>>>(offs, bcur);
    k_fill1<<<FB, 256, 0, stream>>>(ei, bcur, pairs);
    k_fill2<<<NBK, 256, 0, stream>>>(pairs, offs, csr);

    // weight prep
    k_prepw<<<16, 256, 0, stream>>>(W1, W2, Whi1, Wlo1, Whi2, Wlo2);

    // conv1: t1 = agg(x); h = relu(t1@W1 + b1)
    k_agg_csr<<<NN / 4, 256, 0, stream>>>(x, csr, offs, deg, dinv, t1);
    k_gemm_mfma<true><<<(NN + 63) / 64, 256, 0, stream>>>(t1, Whi1, Wlo1, b1, h, NN);

    // conv2: t1 = agg(h); out = t1@W2 + b2
    k_agg_csr<<<NN / 4, 256, 0, stream>>>(h, csr, offs, deg, dinv, t1);
    k_gemm_mfma<false><<<(NN + 63) / 64, 256, 0, stream>>>(t1, Whi2, Wlo2, b2, out, NN);
}